// Round 4
// baseline (240.506 us; speedup 1.0000x reference)
//
#include <hip/hip_runtime.h>
#include <hip/hip_bf16.h>
#include <math.h>

#define B_ROWS 4096
#define D_DIM 512
#define TWO_B 8192
#define HW_N 256
#define BASE_T 0.07f
#define ALPHA_C 0.5f
#define LOG2E 1.44269504088896340736f

typedef float v4f __attribute__((ext_vector_type(4)));
typedef int   v4i __attribute__((ext_vector_type(4)));
typedef int   v8i __attribute__((ext_vector_type(8)));

__device__ __forceinline__ float fast_exp2(float x) {
#if __has_builtin(__builtin_amdgcn_exp2f)
    return __builtin_amdgcn_exp2f(x);
#else
    return exp2f(x);
#endif
}

// ---------------------------------------------------------------------------
// Kernel 1: normalize, temps, pos_sim; write X as packed fp8 e4m3 (OCP).
// One block (256 thr) per sample row b; thread t handles dims 2t, 2t+1.
// Block 0 thread 0 also zeroes out[0] for finish1's atomic accumulation.
// ---------------------------------------------------------------------------
__global__ __launch_bounds__(256) void prep_kernel(
    const float* __restrict__ emb1, const float* __restrict__ emb2,
    const float* __restrict__ att, unsigned short* __restrict__ X8,
    float* __restrict__ inv_temp, float* __restrict__ pos,
    float* __restrict__ out)
{
    const int b = blockIdx.x;
    const int t = threadIdx.x;
    const float2 a1 = ((const float2*)(emb1 + (size_t)b * D_DIM))[t];
    const float2 a2 = ((const float2*)(emb2 + (size_t)b * D_DIM))[t];
    float av = att[(size_t)b * HW_N + t];
    float s1  = a1.x * a1.x + a1.y * a1.y;
    float s2  = a2.x * a2.x + a2.y * a2.y;
    float s12 = a1.x * a2.x + a1.y * a2.y;
    #pragma unroll
    for (int m = 1; m < 64; m <<= 1) {
        s1  += __shfl_xor(s1, m, 64);
        s2  += __shfl_xor(s2, m, 64);
        s12 += __shfl_xor(s12, m, 64);
        av  += __shfl_xor(av, m, 64);
    }
    __shared__ float red[4][4];
    const int w = t >> 6, lane = t & 63;
    if (lane == 0) { red[w][0] = s1; red[w][1] = s2; red[w][2] = s12; red[w][3] = av; }
    __syncthreads();
    const float T1  = red[0][0] + red[1][0] + red[2][0] + red[3][0];
    const float T2  = red[0][1] + red[1][1] + red[2][1] + red[3][1];
    const float T12 = red[0][2] + red[1][2] + red[2][2] + red[3][2];
    const float Ta  = red[0][3] + red[1][3] + red[2][3] + red[3][3];
    const float i1 = 1.0f / fmaxf(sqrtf(T1), 1e-12f);
    const float i2 = 1.0f / fmaxf(sqrtf(T2), 1e-12f);
    const float it = 1.0f / (BASE_T * (1.0f + ALPHA_C * (Ta * (1.0f / 256.0f))));
    const int p1 = __builtin_amdgcn_cvt_pk_fp8_f32(a1.x * i1, a1.y * i1, 0, false);
    const int p2 = __builtin_amdgcn_cvt_pk_fp8_f32(a2.x * i2, a2.y * i2, 0, false);
    X8[(size_t)b * 256 + t]            = (unsigned short)(p1 & 0xffff);
    X8[(size_t)(b + B_ROWS) * 256 + t] = (unsigned short)(p2 & 0xffff);
    if (t == 0) {
        inv_temp[b] = it * LOG2E;
        inv_temp[b + B_ROWS] = it * LOG2E;
        pos[b] = (T12 * i1 * i2) * it;       // ln units, exact fp32
        if (b == 0) out[0] = 0.0f;           // for finish1's atomicAdd
    }
}

// ---------------------------------------------------------------------------
// Kernel 2: triangular Gram (rb<=cb) in FP8 e4m3.
// R8: R6 skeleton + R3's PROVEN pieces only.
//  - MX mfma_scale_f32_16x16x128_f8f6f4, unit scales (absmax 0.0 in R3):
//    halves MFMA-pipe time, 4x fewer MFMA issues.
//  - Both A and B staged via glds into a SINGLE 32 KB buffer, BK=128
//    (LDS = 2 x 128 rows x 128 B). Global fragment streaming is ruled out
//    by Little's law (needs ~14 KB/CU in flight; reg loads give ~3 KB);
//    R7's spill came from hoisted global loads in the unrolled loop.
//  - r&7 XOR unit swizzle + two-v4i canonical fragment reads (R3-proven):
//    bank-uniform 8 accesses/bank on reads.
//  - stage(p+1) issued between read-barrier and MFMAs so MFMAs cover part
//    of the glds flight; 3 blocks/CU (launch_bounds(256,3), no spill) give
//    cross-block overlap for the rest.
// Epilogues byte-identical to R6 (16x16 C/D layout is shape-determined).
// ---------------------------------------------------------------------------
__device__ __forceinline__ void gload_lds16(const void* g, void* s) {
    __builtin_amdgcn_global_load_lds(
        (const __attribute__((address_space(1))) unsigned int*)g,
        (__attribute__((address_space(3))) unsigned int*)s,
        16, 0, 0);
}

__global__ __launch_bounds__(256, 3) void gram_kernel(
    const unsigned char* __restrict__ X8,
    const float* __restrict__ inv_temp,
    float* __restrict__ partial)
{
    // --- XCD-contiguous remap: 2080 = 8 XCDs x 260 contiguous tri-ids ---
    const int bid = (blockIdx.x & 7) * 260 + (blockIdx.x >> 3);
    // --- triangular index: bid -> (rb, cb), rb <= cb ---
    int rb = (int)((129.0f - sqrtf(129.0f * 129.0f - 8.0f * (float)bid)) * 0.5f);
    rb = rb < 0 ? 0 : (rb > 63 ? 63 : rb);
    while (rb > 0 && (rb * (129 - rb)) / 2 > bid) rb--;
    while (rb < 63 && ((rb + 1) * (129 - (rb + 1))) / 2 <= bid) rb++;
    const int cb = rb + (bid - (rb * (129 - rb)) / 2);

    // single-buffered BK=128: 128 rows x 128 B each = 16 KB + 16 KB
    __shared__ unsigned char smA[16384];
    __shared__ unsigned char smB[16384];

    const int rowBase = rb * 128;
    const int colBase = cb * 128;

    const int tid  = threadIdx.x;
    const int w    = tid >> 6;
    const int lane = tid & 63;
    const int quad = lane >> 4;
    const int t    = lane & 15;
    const int wm   = w >> 1;
    const int wn   = w & 1;

    // staging roles: each glds covers 8 rows x 8 units(16B) = 1 KB
    const int lr = lane >> 3;               // row within 8-row chunk
    const int gc = (lane & 7) ^ lr;         // swizzled source unit (s(r)=r&7)

    const unsigned char* Arow0 = X8 + (size_t)rowBase * D_DIM;
    const unsigned char* Brow0 = X8 + (size_t)colBase * D_DIM;

    v4f acc[4][4];
    #pragma unroll
    for (int a = 0; a < 4; a++)
        #pragma unroll
        for (int b2 = 0; b2 < 4; b2++)
            acc[a][b2] = v4f{0.0f, 0.0f, 0.0f, 0.0f};

    // read-side addressing: row r = base+t, want global units {2q, 2q+1};
    // phys unit of global u is u ^ (r&7), r&7 = t&7 for both A and B.
    const int off0 = (((quad * 2) ^ (t & 7)))     * 16;
    const int off1 = (((quad * 2) ^ (t & 7)) ^ 1) * 16;
    const int aRowB = (wm * 64 + t) * 128;  // + mi*2048 per mi
    const int bRowB = (wn * 64 + t) * 128;  // + ni*2048 per ni

    // ---- prologue: stage k-window 0 ----
    #pragma unroll
    for (int j = 0; j < 4; j++) {
        const int g = w * 4 + j;            // chunk 0..15 (8 rows each)
        const size_t src = (size_t)(g * 8 + lr) * D_DIM + gc * 16;
        gload_lds16(Arow0 + src, &smA[g * 1024]);
        gload_lds16(Brow0 + src, &smB[g * 1024]);
    }
    __syncthreads();

    // ---- 4-step main loop (K=128 per step), single buffer ----
    #pragma unroll
    for (int p = 0; p < 4; p++) {
        // load ALL fragments of this step into registers (canonical order)
        v8i aF[4], bF[4];
        #pragma unroll
        for (int mi = 0; mi < 4; mi++) {
            v4i lo = *(const v4i*)&smA[aRowB + mi * 2048 + off0];
            v4i hi = *(const v4i*)&smA[aRowB + mi * 2048 + off1];
            aF[mi] = __builtin_shufflevector(lo, hi, 0, 1, 2, 3, 4, 5, 6, 7);
        }
        #pragma unroll
        for (int ni = 0; ni < 4; ni++) {
            v4i lo = *(const v4i*)&smB[bRowB + ni * 2048 + off0];
            v4i hi = *(const v4i*)&smB[bRowB + ni * 2048 + off1];
            bF[ni] = __builtin_shufflevector(lo, hi, 0, 1, 2, 3, 4, 5, 6, 7);
        }

        if (p < 3) {
            __syncthreads();                // all waves done reading LDS
            const int kn = (p + 1) * 128;   // restage same buffer
            #pragma unroll
            for (int j = 0; j < 4; j++) {
                const int g = w * 4 + j;
                const size_t src = (size_t)(g * 8 + lr) * D_DIM + kn + gc * 16;
                gload_lds16(Arow0 + src, &smA[g * 1024]);
                gload_lds16(Brow0 + src, &smB[g * 1024]);
            }
        }

        // MFMAs (register-only) overlap the glds flight
        #pragma unroll
        for (int ni = 0; ni < 4; ni++)
            #pragma unroll
            for (int mi = 0; mi < 4; mi++)
                acc[mi][ni] = __builtin_amdgcn_mfma_scale_f32_16x16x128_f8f6f4(
                    aF[mi], bF[ni], acc[mi][ni],
                    0, 0,                    // cbsz=fp8, blgp=fp8
                    0, 0x7F7F7F7F,           // A scale = 2^0
                    0, 0x7F7F7F7F);          // B scale = 2^0

        if (p < 3) __syncthreads();         // drain glds before next reads
    }

    // ---- Epilogue 1: row sums (temp_i), slice 2*cb+wn ----
    v4f itv[4];
    #pragma unroll
    for (int mi = 0; mi < 4; mi++)
        itv[mi] = *(const v4f*)&inv_temp[rowBase + wm * 64 + mi * 16 + quad * 4];

    float* prow = partial + (size_t)(cb * 2 + wn) * TWO_B;
    #pragma unroll
    for (int mi = 0; mi < 4; mi++) {
        #pragma unroll
        for (int r = 0; r < 4; r++) {
            const int i = rowBase + wm * 64 + mi * 16 + quad * 4 + r;
            const float it = itv[mi][r];
            float s = 0.0f;
            #pragma unroll
            for (int ni = 0; ni < 4; ni++) {
                const int j = colBase + wn * 64 + ni * 16 + t;
                const float v = fast_exp2(acc[mi][ni][r] * it);
                s += (i == j) ? 0.0f : v;
            }
            s += __shfl_xor(s, 1, 64);
            s += __shfl_xor(s, 2, 64);
            s += __shfl_xor(s, 4, 64);
            s += __shfl_xor(s, 8, 64);
            if (t == 0) prow[i] = s;
        }
    }

    // ---- Epilogue 2 (off-diag): col sums (temp_j), slice 2*rb+wm ----
    if (rb != cb) {
        float itj[4];
        float cs[4] = {0.0f, 0.0f, 0.0f, 0.0f};
        #pragma unroll
        for (int ni = 0; ni < 4; ni++)
            itj[ni] = inv_temp[colBase + wn * 64 + ni * 16 + t];
        #pragma unroll
        for (int mi = 0; mi < 4; mi++)
            #pragma unroll
            for (int r = 0; r < 4; r++)
                #pragma unroll
                for (int ni = 0; ni < 4; ni++)
                    cs[ni] += fast_exp2(acc[mi][ni][r] * itj[ni]);
        float* pcol = partial + (size_t)(rb * 2 + wm) * TWO_B;
        #pragma unroll
        for (int ni = 0; ni < 4; ni++) {
            cs[ni] += __shfl_xor(cs[ni], 16, 64);
            cs[ni] += __shfl_xor(cs[ni], 32, 64);
            if (quad == 0) pcol[colBase + wn * 64 + ni * 16 + t] = cs[ni];
        }
    }
}

// ---------------------------------------------------------------------------
// Kernel 3: denom = sum of 128 slices; loss_i = log(denom) - pos;
// block sum atomically accumulated into out[0] (zeroed by prep_kernel).
// ---------------------------------------------------------------------------
__global__ __launch_bounds__(256) void finish1(
    const float* __restrict__ partial, const float* __restrict__ pos,
    float* __restrict__ out)
{
    const int i = blockIdx.x * 256 + threadIdx.x;
    float d = 0.0f;
    #pragma unroll 8
    for (int s = 0; s < 128; s++) d += partial[(size_t)s * TWO_B + i];
    float li = logf(d) - pos[i & (B_ROWS - 1)];
    #pragma unroll
    for (int m = 1; m < 64; m <<= 1) li += __shfl_xor(li, m, 64);
    __shared__ float red[4];
    const int w = threadIdx.x >> 6, lane = threadIdx.x & 63;
    if (lane == 0) red[w] = li;
    __syncthreads();
    if (threadIdx.x == 0)
        atomicAdd(out, (red[0] + red[1] + red[2] + red[3]) * (1.0f / 8192.0f));
}

// ---------------------------------------------------------------------------
extern "C" void kernel_launch(void* const* d_in, const int* in_sizes, int n_in,
                              void* d_out, int out_size, void* d_ws, size_t ws_size,
                              hipStream_t stream) {
    const float* emb1 = (const float*)d_in[0];
    const float* emb2 = (const float*)d_in[1];
    const float* att  = (const float*)d_in[2];
    float* out = (float*)d_out;

    char* ws = (char*)d_ws;
    // layout: X8 fp8 [8192*512] = 4,194,304 B
    //         inv_temp f32 [8192]      -> +32,768
    //         pos f32 [4096]           -> +16,384
    //         partial f32 [128*8192]   -> +4,194,304
    unsigned short* X8 = (unsigned short*)ws;
    float* inv_temp    = (float*)(ws + 4194304);
    float* pos         = (float*)(ws + 4194304 + 32768);
    float* partial     = (float*)(ws + 4194304 + 32768 + 16384);

    prep_kernel<<<B_ROWS, 256, 0, stream>>>(emb1, emb2, att, X8, inv_temp, pos, out);
    gram_kernel<<<2080, 256, 0, stream>>>((const unsigned char*)X8, inv_temp, partial);
    finish1<<<TWO_B / 256, 256, 0, stream>>>(partial, pos, out);
}

// Round 5
// 121.274 us; speedup vs baseline: 1.9832x; 1.9832x over previous
//
#include <hip/hip_runtime.h>
#include <hip/hip_bf16.h>
#include <math.h>

#define B_ROWS 4096
#define D_DIM 512
#define TWO_B 8192
#define HW_N 256
#define BASE_T 0.07f
#define ALPHA_C 0.5f
#define LOG2E 1.44269504088896340736f

typedef float v4f __attribute__((ext_vector_type(4)));

__device__ __forceinline__ float fast_exp2(float x) {
#if __has_builtin(__builtin_amdgcn_exp2f)
    return __builtin_amdgcn_exp2f(x);
#else
    return exp2f(x);
#endif
}

// ---------------------------------------------------------------------------
// Kernel 1: normalize, temps, pos_sim; write X as packed fp8 e4m3 (OCP).
// One block (256 thr) per sample row b; thread t handles dims 2t, 2t+1.
// Block 0 thread 0 also zeroes out[0] for finish1's atomic accumulation.
// ---------------------------------------------------------------------------
__global__ __launch_bounds__(256) void prep_kernel(
    const float* __restrict__ emb1, const float* __restrict__ emb2,
    const float* __restrict__ att, unsigned short* __restrict__ X8,
    float* __restrict__ inv_temp, float* __restrict__ pos,
    float* __restrict__ out)
{
    const int b = blockIdx.x;
    const int t = threadIdx.x;
    const float2 a1 = ((const float2*)(emb1 + (size_t)b * D_DIM))[t];
    const float2 a2 = ((const float2*)(emb2 + (size_t)b * D_DIM))[t];
    float av = att[(size_t)b * HW_N + t];
    float s1  = a1.x * a1.x + a1.y * a1.y;
    float s2  = a2.x * a2.x + a2.y * a2.y;
    float s12 = a1.x * a2.x + a1.y * a2.y;
    #pragma unroll
    for (int m = 1; m < 64; m <<= 1) {
        s1  += __shfl_xor(s1, m, 64);
        s2  += __shfl_xor(s2, m, 64);
        s12 += __shfl_xor(s12, m, 64);
        av  += __shfl_xor(av, m, 64);
    }
    __shared__ float red[4][4];
    const int w = t >> 6, lane = t & 63;
    if (lane == 0) { red[w][0] = s1; red[w][1] = s2; red[w][2] = s12; red[w][3] = av; }
    __syncthreads();
    const float T1  = red[0][0] + red[1][0] + red[2][0] + red[3][0];
    const float T2  = red[0][1] + red[1][1] + red[2][1] + red[3][1];
    const float T12 = red[0][2] + red[1][2] + red[2][2] + red[3][2];
    const float Ta  = red[0][3] + red[1][3] + red[2][3] + red[3][3];
    const float i1 = 1.0f / fmaxf(sqrtf(T1), 1e-12f);
    const float i2 = 1.0f / fmaxf(sqrtf(T2), 1e-12f);
    const float it = 1.0f / (BASE_T * (1.0f + ALPHA_C * (Ta * (1.0f / 256.0f))));
    const int p1 = __builtin_amdgcn_cvt_pk_fp8_f32(a1.x * i1, a1.y * i1, 0, false);
    const int p2 = __builtin_amdgcn_cvt_pk_fp8_f32(a2.x * i2, a2.y * i2, 0, false);
    X8[(size_t)b * 256 + t]            = (unsigned short)(p1 & 0xffff);
    X8[(size_t)(b + B_ROWS) * 256 + t] = (unsigned short)(p2 & 0xffff);
    if (t == 0) {
        inv_temp[b] = it * LOG2E;
        inv_temp[b + B_ROWS] = it * LOG2E;
        pos[b] = (T12 * i1 * i2) * it;       // ln units, exact fp32
        if (b == 0) out[0] = 0.0f;           // for finish1's atomicAdd
    }
}

// ---------------------------------------------------------------------------
// Kernel 2: triangular Gram (rb<=cb) in FP8 e4m3.
// R9 = R6 kernel (proven: 45.2 us, absmax 0, FETCH 13 MB) with ONE change:
// depth-2 counted-vmcnt pipeline (T4) over 3 LDS buffers (48 KB, 3 blk/CU).
// Per step p: issue stage(p+2) -> compute buf[p%3] -> s_waitcnt vmcnt(4)
// (drains own stage(p+1)'s 4 glds; stage(p+2)'s 4 stay IN FLIGHT across the
// barrier) -> raw s_barrier. Every wave issues exactly 4 glds per stage, so
// per-wave vmcnt(4) + barrier proves all waves' stage(p+1) complete.
// "memory"-clobber fences at each sync stop VMEM/ds_read hoisting (R7
// lesson). MX path abandoned: R7+R8 both showed ~290 MB scratch churn from
// the mfma_scale builtin under two different structures.
// ---------------------------------------------------------------------------
__device__ __forceinline__ void gload_lds16(const void* g, void* s) {
    __builtin_amdgcn_global_load_lds(
        (const __attribute__((address_space(1))) unsigned int*)g,
        (__attribute__((address_space(3))) unsigned int*)s,
        16, 0, 0);
}

__global__ __launch_bounds__(256, 3) void gram_kernel(
    const unsigned char* __restrict__ X8,
    const float* __restrict__ inv_temp,
    float* __restrict__ partial)
{
    // --- XCD-contiguous remap: 2080 = 8 XCDs x 260 contiguous tri-ids ---
    const int bid = (blockIdx.x & 7) * 260 + (blockIdx.x >> 3);
    // --- triangular index: bid -> (rb, cb), rb <= cb ---
    int rb = (int)((129.0f - sqrtf(129.0f * 129.0f - 8.0f * (float)bid)) * 0.5f);
    rb = rb < 0 ? 0 : (rb > 63 ? 63 : rb);
    while (rb > 0 && (rb * (129 - rb)) / 2 > bid) rb--;
    while (rb < 63 && ((rb + 1) * (129 - (rb + 1))) / 2 <= bid) rb++;
    const int cb = rb + (bid - (rb * (129 - rb)) / 2);

    // 3 buffers x 128 rows x 64 B per matrix = 3 x 8 KB x 2 = 48 KB
    __shared__ unsigned char smA[3][8192];
    __shared__ unsigned char smB[3][8192];

    const int rowBase = rb * 128;
    const int colBase = cb * 128;

    const int tid  = threadIdx.x;
    const int w    = tid >> 6;
    const int lane = tid & 63;
    const int quad = lane >> 4;
    const int t    = lane & 15;
    const int wm   = w >> 1;
    const int wn   = w & 1;

    // staging roles: each glds covers 16 rows x 4 units(16B) = 1 KB
    const int lr = lane >> 2;   // 0..15 (row within group)
    const int su = lane & 3;    // 0..3  (16B unit within row)

    const unsigned char* Arow0 = X8 + (size_t)rowBase * D_DIM;
    const unsigned char* Brow0 = X8 + (size_t)colBase * D_DIM;

    v4f acc[4][4];
    #pragma unroll
    for (int a = 0; a < 4; a++)
        #pragma unroll
        for (int b2 = 0; b2 < 4; b2++)
            acc[a][b2] = v4f{0.0f, 0.0f, 0.0f, 0.0f};

    const int hb = (t >> 1) & 3;            // read-side swizzle key
    const int aBase = (wm * 64 + t) * 64;   // LDS row base (A), rows mi*16 apart
    const int bBase = (wn * 64 + t) * 64;

// stage k-window KK (bytes) of both tiles into buffer BUF (4 glds/wave)
#define STAGE(BUF, KK) do {                                                   \
    _Pragma("unroll")                                                         \
    for (int j = 0; j < 2; j++) {                                             \
        const int g = w * 2 + j;            /* row group 0..7 (16 rows) */    \
        const int r = g * 16 + lr;                                            \
        const int gc = su ^ ((r >> 1) & 3); /* XOR swizzle via global unit */ \
        gload_lds16(Arow0 + (size_t)r * D_DIM + (KK) + gc * 16,               \
                    &smA[BUF][g * 1024]);                                     \
        gload_lds16(Brow0 + (size_t)r * D_DIM + (KK) + gc * 16,               \
                    &smB[BUF][g * 1024]);                                     \
    }                                                                         \
} while (0)

// compute one BK=64 step from buffer BUF (32 MFMAs/wave)
#define COMPUTE(BUF) do {                                                     \
    _Pragma("unroll")                                                         \
    for (int s = 0; s < 2; s++) {                                             \
        const int pu = (s * 2 + (quad >> 1)) ^ hb;                            \
        const int off = pu * 16 + (quad & 1) * 8;                             \
        long aF[4], bF[4];                                                    \
        _Pragma("unroll")                                                     \
        for (int mi = 0; mi < 4; mi++)                                        \
            aF[mi] = *(const long*)&smA[BUF][aBase + mi * 1024 + off];        \
        _Pragma("unroll")                                                     \
        for (int ni = 0; ni < 4; ni++)                                        \
            bF[ni] = *(const long*)&smB[BUF][bBase + ni * 1024 + off];        \
        _Pragma("unroll")                                                     \
        for (int mi = 0; mi < 4; mi++)                                        \
            _Pragma("unroll")                                                 \
            for (int ni = 0; ni < 4; ni++)                                    \
                acc[mi][ni] = __builtin_amdgcn_mfma_f32_16x16x32_fp8_fp8(     \
                    aF[mi], bF[ni], acc[mi][ni], 0, 0, 0);                    \
    }                                                                         \
} while (0)

#define SYNC_N(N) do {                                                        \
    asm volatile("s_waitcnt vmcnt(" #N ")" ::: "memory");                     \
    __builtin_amdgcn_s_barrier();                                             \
    asm volatile("" ::: "memory");                                            \
} while (0)

    // ---- prologue: stage steps 0 and 1 ----
    STAGE(0, 0);
    STAGE(1, 64);
    SYNC_N(4);                  // stage0 done; stage1 (4 glds) in flight

    // ---- steady: 6 full steps, depth-2 prefetch ----
    STAGE(2, 128);  COMPUTE(0);  SYNC_N(4);    // p=0
    STAGE(0, 192);  COMPUTE(1);  SYNC_N(4);    // p=1
    STAGE(1, 256);  COMPUTE(2);  SYNC_N(4);    // p=2
    STAGE(2, 320);  COMPUTE(0);  SYNC_N(4);    // p=3
    STAGE(0, 384);  COMPUTE(1);  SYNC_N(4);    // p=4
    STAGE(1, 448);  COMPUTE(2);  SYNC_N(4);    // p=5
    // ---- drain ----
    COMPUTE(0);     SYNC_N(0);                 // p=6 (stage7 drains)
    COMPUTE(1);                                // p=7 (no barrier needed)

#undef STAGE
#undef COMPUTE
#undef SYNC_N

    // ---- Epilogue 1: row sums (temp_i), slice 2*cb+wn ----
    v4f itv[4];
    #pragma unroll
    for (int mi = 0; mi < 4; mi++)
        itv[mi] = *(const v4f*)&inv_temp[rowBase + wm * 64 + mi * 16 + quad * 4];

    float* prow = partial + (size_t)(cb * 2 + wn) * TWO_B;
    #pragma unroll
    for (int mi = 0; mi < 4; mi++) {
        #pragma unroll
        for (int r = 0; r < 4; r++) {
            const int i = rowBase + wm * 64 + mi * 16 + quad * 4 + r;
            const float it = itv[mi][r];
            float s = 0.0f;
            #pragma unroll
            for (int ni = 0; ni < 4; ni++) {
                const int j = colBase + wn * 64 + ni * 16 + t;
                const float v = fast_exp2(acc[mi][ni][r] * it);
                s += (i == j) ? 0.0f : v;
            }
            s += __shfl_xor(s, 1, 64);
            s += __shfl_xor(s, 2, 64);
            s += __shfl_xor(s, 4, 64);
            s += __shfl_xor(s, 8, 64);
            if (t == 0) prow[i] = s;
        }
    }

    // ---- Epilogue 2 (off-diag): col sums (temp_j), slice 2*rb+wm ----
    if (rb != cb) {
        float itj[4];
        float cs[4] = {0.0f, 0.0f, 0.0f, 0.0f};
        #pragma unroll
        for (int ni = 0; ni < 4; ni++)
            itj[ni] = inv_temp[colBase + wn * 64 + ni * 16 + t];
        #pragma unroll
        for (int mi = 0; mi < 4; mi++)
            #pragma unroll
            for (int r = 0; r < 4; r++)
                #pragma unroll
                for (int ni = 0; ni < 4; ni++)
                    cs[ni] += fast_exp2(acc[mi][ni][r] * itj[ni]);
        float* pcol = partial + (size_t)(rb * 2 + wm) * TWO_B;
        #pragma unroll
        for (int ni = 0; ni < 4; ni++) {
            cs[ni] += __shfl_xor(cs[ni], 16, 64);
            cs[ni] += __shfl_xor(cs[ni], 32, 64);
            if (quad == 0) pcol[colBase + wn * 64 + ni * 16 + t] = cs[ni];
        }
    }
}

// ---------------------------------------------------------------------------
// Kernel 3: denom = sum of 128 slices; loss_i = log(denom) - pos;
// block sum atomically accumulated into out[0] (zeroed by prep_kernel).
// ---------------------------------------------------------------------------
__global__ __launch_bounds__(256) void finish1(
    const float* __restrict__ partial, const float* __restrict__ pos,
    float* __restrict__ out)
{
    const int i = blockIdx.x * 256 + threadIdx.x;
    float d = 0.0f;
    #pragma unroll 8
    for (int s = 0; s < 128; s++) d += partial[(size_t)s * TWO_B + i];
    float li = logf(d) - pos[i & (B_ROWS - 1)];
    #pragma unroll
    for (int m = 1; m < 64; m <<= 1) li += __shfl_xor(li, m, 64);
    __shared__ float red[4];
    const int w = threadIdx.x >> 6, lane = threadIdx.x & 63;
    if (lane == 0) red[w] = li;
    __syncthreads();
    if (threadIdx.x == 0)
        atomicAdd(out, (red[0] + red[1] + red[2] + red[3]) * (1.0f / 8192.0f));
}

// ---------------------------------------------------------------------------
extern "C" void kernel_launch(void* const* d_in, const int* in_sizes, int n_in,
                              void* d_out, int out_size, void* d_ws, size_t ws_size,
                              hipStream_t stream) {
    const float* emb1 = (const float*)d_in[0];
    const float* emb2 = (const float*)d_in[1];
    const float* att  = (const float*)d_in[2];
    float* out = (float*)d_out;

    char* ws = (char*)d_ws;
    // layout: X8 fp8 [8192*512] = 4,194,304 B
    //         inv_temp f32 [8192]      -> +32,768
    //         pos f32 [4096]           -> +16,384
    //         partial f32 [128*8192]   -> +4,194,304
    unsigned short* X8 = (unsigned short*)ws;
    float* inv_temp    = (float*)(ws + 4194304);
    float* pos         = (float*)(ws + 4194304 + 32768);
    float* partial     = (float*)(ws + 4194304 + 32768 + 16384);

    prep_kernel<<<B_ROWS, 256, 0, stream>>>(emb1, emb2, att, X8, inv_temp, pos, out);
    gram_kernel<<<2080, 256, 0, stream>>>((const unsigned char*)X8, inv_temp, partial);
    finish1<<<TWO_B / 256, 256, 0, stream>>>(partial, pos, out);
}